// Round 6
// baseline (3204.370 us; speedup 1.0000x reference)
//
#include <hip/hip_runtime.h>
#include <hip/hip_cooperative_groups.h>

namespace cg = cooperative_groups;

// GraphLSTM persistent cooperative kernel, v2. S=32, N=65536.
// 256 blocks x 512 threads = 1 block/CU (conservative cooperative validation).
// Each wave owns TWO 16-node tiles; B-fragments shared across tiles.
// States in registers: gc,cc f32 D-frag layout; gh,ch bf16 A-frags
// (re-transposed per step via per-wave LDS slice). Only cross-block data:
// 64-float gh-sum per step (double-buffered partials + one grid.sync).
// FALLBACK: if hipLaunchCooperativeKernel fails validation, run the proven
// round-4 per-step kernel path (k_step x 33).

#define Sx    32
#define Nx    65536
#define OUTx  5
#define KG    96              // graph gates K: [gemb(32) | gh(64)]
#define KC    160             // cell gates K:  [dyn(32) | gh(64) | ch(64)]

#define GRIDP 256             // persistent: 256 blocks = 1/CU
#define TPBP  512

#define GRIDF 512             // fallback (round-4 k_step)
#define TPBF  512
#define NPBF  128

typedef __attribute__((ext_vector_type(4))) float f32x4;
typedef __attribute__((ext_vector_type(8))) short bf16x8;
typedef unsigned short ushort;
typedef unsigned int uint;

__device__ __forceinline__ float sigm(float x) {
    return __frcp_rn(1.f + __expf(-x));
}
__device__ __forceinline__ float tanh_fast(float x) {
    return fmaf(-2.f, __frcp_rn(1.f + __expf(2.f * x)), 1.f);
}
__device__ __forceinline__ ushort f2b(float x) {
    uint u = __float_as_uint(x);
    u += 0x7fffu + ((u >> 16) & 1u);   // RNE
    return (ushort)(u >> 16);
}

// ---------------- weight prep (once per launch, parallel) ----------------
__global__ __launch_bounds__(256) void k_prep(
    const float* __restrict__ Wih_g, const float* __restrict__ Whh_g,
    const float* __restrict__ bih_g, const float* __restrict__ bhh_g,
    const float* __restrict__ wgr,
    const float* __restrict__ Wih_c, const float* __restrict__ Whh_c,
    const float* __restrict__ bih_c, const float* __restrict__ bhh_c,
    ushort* __restrict__ Wg, ushort* __restrict__ Wc,
    float* __restrict__ Wfold2,
    float* __restrict__ bsum_g, float* __restrict__ bC0)
{
    const int tid = blockIdx.x * 256 + threadIdx.x;
    const int nt = gridDim.x * 256;
    for (int idx = tid; idx < 256 * KG; idx += nt) {
        int col = idx / KG, k = idx % KG;
        float v = (k < 32) ? Wih_g[col * 32 + k] : Whh_g[col * 64 + (k - 32)];
        Wg[idx] = f2b(v);
    }
    for (int idx = tid; idx < 256 * KC; idx += nt) {
        int col = idx / KC, k = idx % KC;
        float v;
        if (k < 32) v = Wih_c[col * 64 + k];
        else if (k < 96) {
            int d = k - 32; float a = 0.f;
            for (int j = 0; j < 32; ++j)
                a = fmaf(wgr[d * 32 + j], Wih_c[col * 64 + 32 + j], a);
            v = -a;   // per-node part of loo is (-gh)
        } else v = Whh_c[col * 64 + (k - 96)];
        Wc[idx] = f2b(v);
    }
    // Wfold2[k][col] = sum_j wgr[k][j] * Wih_c[col][32+j]   (f32, S-bias path)
    for (int idx = tid; idx < 64 * 256; idx += nt) {
        int k = idx >> 8, col = idx & 255;
        float a = 0.f;
        for (int j = 0; j < 32; ++j)
            a = fmaf(wgr[k * 32 + j], Wih_c[col * 64 + 32 + j], a);
        Wfold2[idx] = a;
    }
    if (tid < 256) {
        bsum_g[tid] = bih_g[tid] + bhh_g[tid];
        bC0[tid]    = bih_c[tid] + bhh_c[tid];
    }
}

struct KP {
    const float* input;
    const float* gh0; const float* gc0; const float* ch0; const float* cc0;
    const float* Wdy; const float* bdy;
    const ushort* Wc; const float* Wfold2; const float* bC0;
    const float* Wout; const float* bo5;
    const float* Wge; const float* bge;
    const ushort* Wg; const float* bsum_g;
    float* pbuf;                       // [2][64][GRIDP]
    float* out0;                       // [S][N][5]
    float* chf; float* ccf; float* ghf; float* gcf;   // [N][64] finals
};

__global__ __launch_bounds__(TPBP, 2) void k_persist(KP P)
{
    cg::grid_group grid = cg::this_grid();
    const int tid = threadIdx.x;
    const int wave = tid >> 6, lane = tid & 63;
    const int c = lane & 15, g4 = lane >> 4;
    const int bid = blockIdx.x;
    const int nb0 = bid * 256 + wave * 32;     // two tiles: nb0, nb0+16

    __shared__ __align__(16) ushort t_lds[8][2][16][72];
    __shared__ float wsum[8][64];
    __shared__ float S_lds[64];
    __shared__ float bias_lds[256];

    // ---- initial states ----
    float gcr[2][4][4], ccr[2][4][4];
    bf16x8 agh[2][2], ach[2][2];
#pragma unroll
    for (int tl = 0; tl < 2; ++tl) {
        const int nb = nb0 + tl * 16;
#pragma unroll
        for (int q = 0; q < 4; ++q)
#pragma unroll
            for (int r = 0; r < 4; ++r) {
                const int n = nb + 4 * g4 + r, d = 16 * q + c;
                gcr[tl][q][r] = P.gc0[n * 64 + d];
                ccr[tl][q][r] = P.cc0[n * 64 + d];
            }
        const int na = nb + c;
#pragma unroll
        for (int j = 0; j < 8; ++j) {
            agh[tl][0][j] = (short)f2b(P.gh0[na * 64 + g4 * 8 + j]);
            agh[tl][1][j] = (short)f2b(P.gh0[na * 64 + 32 + g4 * 8 + j]);
            ach[tl][0][j] = (short)f2b(P.ch0[na * 64 + g4 * 8 + j]);
            ach[tl][1][j] = (short)f2b(P.ch0[na * 64 + 32 + g4 * 8 + j]);
        }
    }

    for (int t = 0; t < Sx; ++t) {
        const float* frame = P.input + (size_t)t * Nx * 2;
        float* pout = P.pbuf + (size_t)(t & 1) * 64 * GRIDP;
        const int lastt = (t == Sx - 1);

        float f0[2], f1[2];
        bf16x8 a0[2];
#pragma unroll
        for (int tl = 0; tl < 2; ++tl) {
            const int na = nb0 + tl * 16 + c;
            f0[tl] = frame[2 * na];
            f1[tl] = frame[2 * na + 1];
#pragma unroll
            for (int j = 0; j < 8; ++j) {
                const int k = g4 * 8 + j;
                float v = fmaf(f1[tl], P.Wge[2 * k + 1],
                               fmaf(f0[tl], P.Wge[2 * k], P.bge[k]));
                a0[tl][j] = (short)f2b(fmaxf(v, 0.f));
            }
        }

        // ===== graph phase (uses agh = gh(t-1)) =====
        float hsq[4];
#pragma unroll
        for (int q = 0; q < 4; ++q) {
            f32x4 acc[2][4];
#pragma unroll
            for (int g = 0; g < 4; ++g) {
                const ushort* wp = P.Wg + (16 * (4 * g + q) + c) * KG + g4 * 8;
                bf16x8 b0 = *(const bf16x8*)(wp);
                bf16x8 b1 = *(const bf16x8*)(wp + 32);
                bf16x8 b2 = *(const bf16x8*)(wp + 64);
#pragma unroll
                for (int tl = 0; tl < 2; ++tl) {
                    f32x4 a = (f32x4){0.f, 0.f, 0.f, 0.f};
                    a = __builtin_amdgcn_mfma_f32_16x16x32_bf16(a0[tl],     b0, a, 0, 0, 0);
                    a = __builtin_amdgcn_mfma_f32_16x16x32_bf16(agh[tl][0], b1, a, 0, 0, 0);
                    a = __builtin_amdgcn_mfma_f32_16x16x32_bf16(agh[tl][1], b2, a, 0, 0, 0);
                    acc[tl][g] = a;
                }
            }
            const int d = 16 * q + c;
            const float bi = P.bsum_g[d], bf = P.bsum_g[64 + d],
                        bg = P.bsum_g[128 + d], bo = P.bsum_g[192 + d];
            float s_r = 0.f;
#pragma unroll
            for (int tl = 0; tl < 2; ++tl)
#pragma unroll
                for (int r = 0; r < 4; ++r) {
                    const float ai = acc[tl][0][r] + bi, af = acc[tl][1][r] + bf,
                                ag = acc[tl][2][r] + bg, ao = acc[tl][3][r] + bo;
                    const float c2 = fmaf(sigm(af), gcr[tl][q][r], sigm(ai) * tanh_fast(ag));
                    gcr[tl][q][r] = c2;
                    const float h2 = sigm(ao) * tanh_fast(c2);
                    t_lds[wave][tl][4 * g4 + r][16 * q + c] = f2b(h2);
                    if (lastt) {
                        const int n = nb0 + tl * 16 + 4 * g4 + r;
                        P.ghf[n * 64 + d] = h2;
                        P.gcf[n * 64 + d] = c2;
                    }
                    s_r += h2;
                }
            hsq[q] = s_r;
        }
#pragma unroll
        for (int q = 0; q < 4; ++q) {
            float v = hsq[q];
            v += __shfl_xor(v, 16);
            v += __shfl_xor(v, 32);
            hsq[q] = v;
        }
        if (g4 == 0) {
#pragma unroll
            for (int q = 0; q < 4; ++q) wsum[wave][16 * q + c] = hsq[q];
        }
        __syncthreads();                       // wsum + t_lds visible
#pragma unroll
        for (int tl = 0; tl < 2; ++tl) {
            agh[tl][0] = *(const bf16x8*)(&t_lds[wave][tl][c][g4 * 8]);
            agh[tl][1] = *(const bf16x8*)(&t_lds[wave][tl][c][32 + g4 * 8]);
        }
        if (tid < 64) {
            float a = 0.f;
#pragma unroll
            for (int w8 = 0; w8 < 8; ++w8) a += wsum[w8][tid];
            pout[tid * GRIDP + bid] = a;
        }

        grid.sync();

        // ===== reduce partials(t) -> S -> cell-gate step bias =====
        {
            const int d2 = tid >> 3, j = tid & 7;
            const f32x4* pp = (const f32x4*)(pout + d2 * GRIDP + j * 32);
            f32x4 a4 = (f32x4){0.f, 0.f, 0.f, 0.f};
#pragma unroll
            for (int k2 = 0; k2 < 8; ++k2) a4 += pp[k2];
            float s = (a4[0] + a4[1]) + (a4[2] + a4[3]);
            s += __shfl_xor(s, 1);
            s += __shfl_xor(s, 2);
            s += __shfl_xor(s, 4);
            if (j == 0) S_lds[d2] = s;
        }
        __syncthreads();
        if (tid < 256) {
            float b = P.bC0[tid];
#pragma unroll
            for (int k = 0; k < 64; ++k)
                b = fmaf(S_lds[k], P.Wfold2[k * 256 + tid], b);
            bias_lds[tid] = b;
        }
        __syncthreads();

        // ===== cell phase (step t; uses agh=gh(t), ach=ch(t-1)) =====
        bf16x8 a0c[2];
#pragma unroll
        for (int tl = 0; tl < 2; ++tl)
#pragma unroll
            for (int j = 0; j < 8; ++j) {
                const int k = g4 * 8 + j;
                float v = fmaf(f1[tl], P.Wdy[2 * k + 1],
                               fmaf(f0[tl], P.Wdy[2 * k], P.bdy[k]));
                a0c[tl][j] = (short)f2b(fmaxf(v, 0.f));
            }
        float po[2][4][OUTx];
#pragma unroll
        for (int tl = 0; tl < 2; ++tl)
#pragma unroll
            for (int r = 0; r < 4; ++r)
#pragma unroll
                for (int o = 0; o < OUTx; ++o) po[tl][r][o] = 0.f;

#pragma unroll
        for (int q = 0; q < 4; ++q) {
            f32x4 acc[2][4];
#pragma unroll
            for (int g = 0; g < 4; ++g) {
                const ushort* wp = P.Wc + (16 * (4 * g + q) + c) * KC + g4 * 8;
                bf16x8 b0 = *(const bf16x8*)(wp);
                bf16x8 b1 = *(const bf16x8*)(wp + 32);
                bf16x8 b2 = *(const bf16x8*)(wp + 64);
                bf16x8 b3 = *(const bf16x8*)(wp + 96);
                bf16x8 b4 = *(const bf16x8*)(wp + 128);
#pragma unroll
                for (int tl = 0; tl < 2; ++tl) {
                    f32x4 a = (f32x4){0.f, 0.f, 0.f, 0.f};
                    a = __builtin_amdgcn_mfma_f32_16x16x32_bf16(a0c[tl],    b0, a, 0, 0, 0);
                    a = __builtin_amdgcn_mfma_f32_16x16x32_bf16(agh[tl][0], b1, a, 0, 0, 0);
                    a = __builtin_amdgcn_mfma_f32_16x16x32_bf16(agh[tl][1], b2, a, 0, 0, 0);
                    a = __builtin_amdgcn_mfma_f32_16x16x32_bf16(ach[tl][0], b3, a, 0, 0, 0);
                    a = __builtin_amdgcn_mfma_f32_16x16x32_bf16(ach[tl][1], b4, a, 0, 0, 0);
                    acc[tl][g] = a;
                }
            }
            const int d = 16 * q + c;
            const float bi = bias_lds[d], bf = bias_lds[64 + d],
                        bg = bias_lds[128 + d], bov = bias_lds[192 + d];
            const float w0 = P.Wout[0 * 64 + d], w1 = P.Wout[1 * 64 + d],
                        w2 = P.Wout[2 * 64 + d], w3 = P.Wout[3 * 64 + d],
                        w4 = P.Wout[4 * 64 + d];
#pragma unroll
            for (int tl = 0; tl < 2; ++tl)
#pragma unroll
                for (int r = 0; r < 4; ++r) {
                    const float ai = acc[tl][0][r] + bi, af = acc[tl][1][r] + bf,
                                ag = acc[tl][2][r] + bg, ao = acc[tl][3][r] + bov;
                    const float c2 = fmaf(sigm(af), ccr[tl][q][r], sigm(ai) * tanh_fast(ag));
                    ccr[tl][q][r] = c2;
                    const float h2 = sigm(ao) * tanh_fast(c2);
                    t_lds[wave][tl][4 * g4 + r][16 * q + c] = f2b(h2);
                    if (lastt) {
                        const int n = nb0 + tl * 16 + 4 * g4 + r;
                        P.chf[n * 64 + d] = h2;
                        P.ccf[n * 64 + d] = c2;
                    }
                    po[tl][r][0] = fmaf(h2, w0, po[tl][r][0]);
                    po[tl][r][1] = fmaf(h2, w1, po[tl][r][1]);
                    po[tl][r][2] = fmaf(h2, w2, po[tl][r][2]);
                    po[tl][r][3] = fmaf(h2, w3, po[tl][r][3]);
                    po[tl][r][4] = fmaf(h2, w4, po[tl][r][4]);
                }
        }
        float* outp = P.out0 + (size_t)t * Nx * OUTx;
#pragma unroll
        for (int tl = 0; tl < 2; ++tl)
#pragma unroll
            for (int r = 0; r < 4; ++r)
#pragma unroll
                for (int o = 0; o < OUTx; ++o) {
                    float v = po[tl][r][o];
                    v += __shfl_xor(v, 1);
                    v += __shfl_xor(v, 2);
                    v += __shfl_xor(v, 4);
                    v += __shfl_xor(v, 8);
                    if (c == 0)
                        outp[(nb0 + tl * 16 + 4 * g4 + r) * OUTx + o] = v + P.bo5[o];
                }
        __syncthreads();                       // t_lds(ch) writes complete
#pragma unroll
        for (int tl = 0; tl < 2; ++tl) {
            ach[tl][0] = *(const bf16x8*)(&t_lds[wave][tl][c][g4 * 8]);
            ach[tl][1] = *(const bf16x8*)(&t_lds[wave][tl][c][32 + g4 * 8]);
        }
        __syncthreads();                       // reads done before next overwrite
    }
}

// ================= FALLBACK: proven round-4 per-step path =================
__global__ __launch_bounds__(256) void k_init(
    const float* __restrict__ gh0, const float* __restrict__ ch0,
    ushort* __restrict__ ghb, ushort* __restrict__ chb)
{
    const int i = blockIdx.x * 256 + threadIdx.x;
    ghb[i] = f2b(gh0[i]);
    chb[i] = f2b(ch0[i]);
}

__global__ __launch_bounds__(TPBF) void k_step(
    const float* __restrict__ frame_c, const float* __restrict__ frame_g,
    const float* __restrict__ pin, float* __restrict__ pout,
    const float* __restrict__ Wdy, const float* __restrict__ bdy,
    const ushort* __restrict__ Wc,
    const float* __restrict__ Wfold2, const float* __restrict__ bC0,
    const float* __restrict__ Wout, const float* __restrict__ bo5,
    const float* __restrict__ Wge, const float* __restrict__ bge,
    const ushort* __restrict__ Wg, const float* __restrict__ bsum_g,
    ushort* __restrict__ ghb, float* __restrict__ gc,
    ushort* __restrict__ chb, float* __restrict__ cc,
    float* __restrict__ ghf, float* __restrict__ chf,
    float* __restrict__ outp,
    int do_cell, int do_graph, int last_cell, int last_graph)
{
    const int tid = threadIdx.x;
    const int wave = tid >> 6, lane = tid & 63;
    const int c = lane & 15, g4 = lane >> 4;
    const int nbase = blockIdx.x * NPBF + wave * 16;
    const int na = nbase + c;

    __shared__ float S_lds[64];
    __shared__ float bias_lds[256];
    __shared__ float wsum[8][64];

    bf16x8 a_gh0 = *(const bf16x8*)(ghb + na * 64 + g4 * 8);
    bf16x8 a_gh1 = *(const bf16x8*)(ghb + na * 64 + 32 + g4 * 8);

    if (do_cell) {
        {
            const int d = tid >> 3, j = tid & 7;
            const f32x4* pp = (const f32x4*)(pin + d * GRIDF + j * 64);
            f32x4 a4 = (f32x4){0.f, 0.f, 0.f, 0.f};
#pragma unroll
            for (int k2 = 0; k2 < 16; ++k2) a4 += pp[k2];
            float s = (a4[0] + a4[1]) + (a4[2] + a4[3]);
            s += __shfl_xor(s, 1);
            s += __shfl_xor(s, 2);
            s += __shfl_xor(s, 4);
            if (j == 0) S_lds[d] = s;
        }
        __syncthreads();
        if (tid < 256) {
            float b = bC0[tid];
#pragma unroll
            for (int k = 0; k < 64; ++k)
                b = fmaf(S_lds[k], Wfold2[k * 256 + tid], b);
            bias_lds[tid] = b;
        }
        __syncthreads();

        const float f0 = frame_c[2 * na], f1 = frame_c[2 * na + 1];
        bf16x8 a0, a3, a4;
#pragma unroll
        for (int j = 0; j < 8; ++j) {
            int k = g4 * 8 + j;
            float v = fmaf(f1, Wdy[2 * k + 1], fmaf(f0, Wdy[2 * k], bdy[k]));
            a0[j] = (short)f2b(fmaxf(v, 0.f));
        }
        a3 = *(const bf16x8*)(chb + na * 64 + g4 * 8);
        a4 = *(const bf16x8*)(chb + na * 64 + 32 + g4 * 8);

        float po[4][OUTx];
#pragma unroll
        for (int r = 0; r < 4; ++r)
#pragma unroll
            for (int o = 0; o < OUTx; ++o) po[r][o] = 0.f;

#pragma unroll
        for (int q = 0; q < 4; ++q) {
            f32x4 acc[4];
#pragma unroll
            for (int g = 0; g < 4; ++g) {
                acc[g] = (f32x4){0.f, 0.f, 0.f, 0.f};
                const ushort* wp = Wc + (16 * (4 * g + q) + c) * KC + g4 * 8;
                bf16x8 b0 = *(const bf16x8*)(wp);
                bf16x8 b1 = *(const bf16x8*)(wp + 32);
                bf16x8 b2 = *(const bf16x8*)(wp + 64);
                bf16x8 b3 = *(const bf16x8*)(wp + 96);
                bf16x8 b4 = *(const bf16x8*)(wp + 128);
                acc[g] = __builtin_amdgcn_mfma_f32_16x16x32_bf16(a0, b0, acc[g], 0, 0, 0);
                acc[g] = __builtin_amdgcn_mfma_f32_16x16x32_bf16(a_gh0, b1, acc[g], 0, 0, 0);
                acc[g] = __builtin_amdgcn_mfma_f32_16x16x32_bf16(a_gh1, b2, acc[g], 0, 0, 0);
                acc[g] = __builtin_amdgcn_mfma_f32_16x16x32_bf16(a3, b3, acc[g], 0, 0, 0);
                acc[g] = __builtin_amdgcn_mfma_f32_16x16x32_bf16(a4, b4, acc[g], 0, 0, 0);
            }
            const int d = 16 * q + c;
            const float bi = bias_lds[d], bf = bias_lds[64 + d],
                        bg = bias_lds[128 + d], bov = bias_lds[192 + d];
            const float w0 = Wout[0 * 64 + d], w1 = Wout[1 * 64 + d],
                        w2 = Wout[2 * 64 + d], w3 = Wout[3 * 64 + d],
                        w4 = Wout[4 * 64 + d];
#pragma unroll
            for (int r = 0; r < 4; ++r) {
                const int n = nbase + 4 * g4 + r;
                const float ai = acc[0][r] + bi, af = acc[1][r] + bf,
                            ag = acc[2][r] + bg, ao = acc[3][r] + bov;
                const float cp = cc[n * 64 + d];
                const float c2 = fmaf(sigm(af), cp, sigm(ai) * tanh_fast(ag));
                cc[n * 64 + d] = c2;
                const float h2 = sigm(ao) * tanh_fast(c2);
                chb[n * 64 + d] = f2b(h2);
                if (last_cell) chf[n * 64 + d] = h2;
                po[r][0] = fmaf(h2, w0, po[r][0]);
                po[r][1] = fmaf(h2, w1, po[r][1]);
                po[r][2] = fmaf(h2, w2, po[r][2]);
                po[r][3] = fmaf(h2, w3, po[r][3]);
                po[r][4] = fmaf(h2, w4, po[r][4]);
            }
        }
#pragma unroll
        for (int r = 0; r < 4; ++r)
#pragma unroll
            for (int o = 0; o < OUTx; ++o) {
                float v = po[r][o];
                v += __shfl_xor(v, 1);
                v += __shfl_xor(v, 2);
                v += __shfl_xor(v, 4);
                v += __shfl_xor(v, 8);
                if (c == 0) outp[(nbase + 4 * g4 + r) * OUTx + o] = v + bo5[o];
            }
    }

    if (do_graph) {
        const float f0 = frame_g[2 * na], f1 = frame_g[2 * na + 1];
        bf16x8 a0;
#pragma unroll
        for (int j = 0; j < 8; ++j) {
            int k = g4 * 8 + j;
            float v = fmaf(f1, Wge[2 * k + 1], fmaf(f0, Wge[2 * k], bge[k]));
            a0[j] = (short)f2b(fmaxf(v, 0.f));
        }
        float hsq[4];
#pragma unroll
        for (int q = 0; q < 4; ++q) {
            f32x4 acc[4];
#pragma unroll
            for (int g = 0; g < 4; ++g) {
                acc[g] = (f32x4){0.f, 0.f, 0.f, 0.f};
                const ushort* wp = Wg + (16 * (4 * g + q) + c) * KG + g4 * 8;
                bf16x8 b0 = *(const bf16x8*)(wp);
                bf16x8 b1 = *(const bf16x8*)(wp + 32);
                bf16x8 b2 = *(const bf16x8*)(wp + 64);
                acc[g] = __builtin_amdgcn_mfma_f32_16x16x32_bf16(a0, b0, acc[g], 0, 0, 0);
                acc[g] = __builtin_amdgcn_mfma_f32_16x16x32_bf16(a_gh0, b1, acc[g], 0, 0, 0);
                acc[g] = __builtin_amdgcn_mfma_f32_16x16x32_bf16(a_gh1, b2, acc[g], 0, 0, 0);
            }
            const int d = 16 * q + c;
            const float bi = bsum_g[d], bf = bsum_g[64 + d],
                        bg = bsum_g[128 + d], bo = bsum_g[192 + d];
            float s_r = 0.f;
#pragma unroll
            for (int r = 0; r < 4; ++r) {
                const int n = nbase + 4 * g4 + r;
                const float ai = acc[0][r] + bi, af = acc[1][r] + bf,
                            ag = acc[2][r] + bg, ao = acc[3][r] + bo;
                const float cp = gc[n * 64 + d];
                const float c2 = fmaf(sigm(af), cp, sigm(ai) * tanh_fast(ag));
                gc[n * 64 + d] = c2;
                const float h2 = sigm(ao) * tanh_fast(c2);
                ghb[n * 64 + d] = f2b(h2);
                if (last_graph) ghf[n * 64 + d] = h2;
                s_r += h2;
            }
            hsq[q] = s_r;
        }
#pragma unroll
        for (int q = 0; q < 4; ++q) {
            float v = hsq[q];
            v += __shfl_xor(v, 16);
            v += __shfl_xor(v, 32);
            hsq[q] = v;
        }
        __syncthreads();
        if (g4 == 0) {
#pragma unroll
            for (int q = 0; q < 4; ++q) wsum[wave][16 * q + c] = hsq[q];
        }
        __syncthreads();
        if (tid < 64) {
            float a = 0.f;
#pragma unroll
            for (int w8 = 0; w8 < 8; ++w8) a += wsum[w8][tid];
            pout[tid * GRIDF + blockIdx.x] = a;
        }
    }
}

extern "C" void kernel_launch(void* const* d_in, const int* in_sizes, int n_in,
                              void* d_out, int out_size, void* d_ws, size_t ws_size,
                              hipStream_t stream) {
    const float* input   = (const float*)d_in[0];   // [S][N][2]
    const float* cell_h0 = (const float*)d_in[1];
    const float* cell_c0 = (const float*)d_in[2];
    const float* graph_h0= (const float*)d_in[3];
    const float* graph_c0= (const float*)d_in[4];
    const float* W_dyn   = (const float*)d_in[5];
    const float* b_dyn   = (const float*)d_in[6];
    const float* W_gemb  = (const float*)d_in[7];
    const float* b_gemb  = (const float*)d_in[8];
    const float* Wih_g   = (const float*)d_in[9];
    const float* Whh_g   = (const float*)d_in[10];
    const float* bih_g   = (const float*)d_in[11];
    const float* bhh_g   = (const float*)d_in[12];
    const float* w_graph = (const float*)d_in[13];
    const float* Wih_c   = (const float*)d_in[14];
    const float* Whh_c   = (const float*)d_in[15];
    const float* bih_c   = (const float*)d_in[16];
    const float* bhh_c   = (const float*)d_in[17];
    const float* W_out   = (const float*)d_in[18];
    const float* b_out   = (const float*)d_in[19];

    float* out0 = (float*)d_out;                        // [S][N][5]
    float* chf = out0 + (size_t)Sx * Nx * OUTx;         // [N][64]
    float* ccf = chf + (size_t)Nx * 64;
    float* ghf = ccf + (size_t)Nx * 64;
    float* gcf = ghf + (size_t)Nx * 64;

    char* w = (char*)d_ws;
    float*  pbufP   = (float*)w;                  w += (size_t)2 * 64 * GRIDP * 4;
    float*  pbufF   = (float*)w;                  w += (size_t)2 * 64 * GRIDF * 4;
    ushort* Wg      = (ushort*)w;                 w += 256 * KG * 2;
    ushort* Wc      = (ushort*)w;                 w += 256 * KC * 2;
    float*  Wfold2  = (float*)w;                  w += 64 * 256 * 4;
    float*  bsum_g  = (float*)w;                  w += 256 * 4;
    float*  bC0     = (float*)w;                  w += 256 * 4;
    ushort* ghb     = (ushort*)w;                 w += (size_t)Nx * 64 * 2;
    ushort* chb     = (ushort*)w;                 w += (size_t)Nx * 64 * 2;

    k_prep<<<64, 256, 0, stream>>>(Wih_g, Whh_g, bih_g, bhh_g, w_graph,
                                   Wih_c, Whh_c, bih_c, bhh_c,
                                   Wg, Wc, Wfold2, bsum_g, bC0);

    KP P;
    P.input = input;
    P.gh0 = graph_h0; P.gc0 = graph_c0; P.ch0 = cell_h0; P.cc0 = cell_c0;
    P.Wdy = W_dyn; P.bdy = b_dyn;
    P.Wc = Wc; P.Wfold2 = Wfold2; P.bC0 = bC0;
    P.Wout = W_out; P.bo5 = b_out;
    P.Wge = W_gemb; P.bge = b_gemb;
    P.Wg = Wg; P.bsum_g = bsum_g;
    P.pbuf = pbufP;
    P.out0 = out0;
    P.chf = chf; P.ccf = ccf; P.ghf = ghf; P.gcf = gcf;

    void* args[] = { &P };
    hipError_t st = hipLaunchCooperativeKernel((void*)k_persist, dim3(GRIDP),
                                               dim3(TPBP), args, 0, stream);
    if (st != hipSuccess) {
        // -------- fallback: proven round-4 per-step path --------
        hipMemcpyAsync(gcf, graph_c0, (size_t)Nx * 64 * sizeof(float),
                       hipMemcpyDeviceToDevice, stream);
        hipMemcpyAsync(ccf, cell_c0, (size_t)Nx * 64 * sizeof(float),
                       hipMemcpyDeviceToDevice, stream);
        k_init<<<(Nx * 64) / 256, 256, 0, stream>>>(graph_h0, cell_h0, ghb, chb);
        for (int i = 0; i <= Sx; ++i) {
            const int do_cell    = (i >= 1);
            const int do_graph   = (i <= Sx - 1);
            const int last_cell  = (i == Sx);
            const int last_graph = (i == Sx - 1);
            const float* frame_c = do_cell  ? input + (size_t)(i - 1) * Nx * 2 : input;
            const float* frame_g = do_graph ? input + (size_t)i * Nx * 2       : input;
            float* pin  = pbufF + (size_t)((i + 1) & 1) * 64 * GRIDF;
            float* pout = pbufF + (size_t)(i & 1) * 64 * GRIDF;
            float* outp = out0 + (size_t)(do_cell ? (i - 1) : 0) * Nx * OUTx;
            k_step<<<GRIDF, TPBF, 0, stream>>>(frame_c, frame_g, pin, pout,
                                               W_dyn, b_dyn, Wc, Wfold2, bC0,
                                               W_out, b_out,
                                               W_gemb, b_gemb, Wg, bsum_g,
                                               ghb, gcf, chb, ccf, ghf, chf,
                                               outp, do_cell, do_graph,
                                               last_cell, last_graph);
        }
    }
}